// Round 23
// baseline (57.027 us; speedup 1.0000x reference)
//
#include <hip/hip_runtime.h>
#include <hip/hip_bf16.h>
#include <hip/hip_fp16.h>
#include <math.h>

#define T_TOKENS 16384
#define DDIM 2048
#define NEXP 64
#define REFINE_TAU 4e-3f
#define NCHK 16                    // 16 chunks of 128 k
#define BLK_TOK 8
#define NBLK (T_TOKENS / BLK_TOK)  // 2048 blocks -> 8 blocks/CU, 32 waves/CU

typedef _Float16 f16x8 __attribute__((ext_vector_type(8)));
typedef float f32x4 __attribute__((ext_vector_type(4)));

__device__ __forceinline__ void gload_lds16(const void* g, void* l) {
    __builtin_amdgcn_global_load_lds(
        (const __attribute__((address_space(1))) void*)g,
        (__attribute__((address_space(3))) void*)l, 16, 0, 0);
}

// ---------------- Kernel 0: W fp32 -> fp16 fragment-ordered panel ----------------
// (r,k) -> pw[((g*64 + ks)*64 + lane)*8 + j], g=r>>4, ks=k>>5,
// lane=((k>>3)&3)*16 + (r&15), j=k&7.  (A-frag mapping, verified R4-R22.)
__global__ __launch_bounds__(256)
void prep_w(const float* __restrict__ W, _Float16* __restrict__ pw) {
    const int t  = blockIdx.x * 256 + threadIdx.x;   // 0..16383
    const int r  = t >> 8;
    const int kc = (t & 255) * 8;
    const float* wp = &W[(size_t)r * DDIM + kc];
    const float4 a = *(const float4*)wp;
    const float4 b = *(const float4*)(wp + 4);
    const float f[8] = { a.x, a.y, a.z, a.w, b.x, b.y, b.z, b.w };
    f16x8 h;
#pragma unroll
    for (int j = 0; j < 8; ++j) h[j] = (_Float16)f[j];
    const int g = r >> 4, ks = kc >> 5;
    const int lane = (((kc >> 3) & 3) << 4) + (r & 15);
    *(f16x8*)&pw[(((size_t)g * 64 + ks) * 64 + lane) * 8] = h;
}

// ---------------- Kernel 1: 8-token max-occupancy gate + fused top-2 ----------------
__device__ __forceinline__ bool better(double va, int ia, double vb, int ib) {
    return (va > vb) || (va == vb && ia < ib);
}

// wave-cooperative f64 dot, 2-pass (32-reg footprint; rare path)
__device__ __forceinline__ double dot_f64_fast(const float* __restrict__ xrow,
                                               const float* __restrict__ wr, int lane) {
    double s0 = 0.0, s1 = 0.0, s2 = 0.0, s3 = 0.0;
#pragma unroll
    for (int h = 0; h < 2; ++h) {
        float4 xa[4], wa[4];
#pragma unroll
        for (int q = 0; q < 4; ++q) {
            xa[q] = *(const float4*)&xrow[(h * 4 + q) * 256 + lane * 4];
            wa[q] = *(const float4*)&wr[(h * 4 + q) * 256 + lane * 4];
        }
#pragma unroll
        for (int q = 0; q < 4; ++q) {
            s0 = fma((double)xa[q].x, (double)wa[q].x, s0);
            s1 = fma((double)xa[q].y, (double)wa[q].y, s1);
            s2 = fma((double)xa[q].z, (double)wa[q].z, s2);
            s3 = fma((double)xa[q].w, (double)wa[q].w, s3);
        }
    }
    double sd = (s0 + s1) + (s2 + s3);
#pragma unroll
    for (int off = 32; off >= 1; off >>= 1) sd += __shfl_xor(sd, off);
    return sd;
}

// stage chunk c into xa[buf]: wave w covers rows 2w, 2w+1 (one 1KB issue)
#define STAGE(buf, c) \
    gload_lds16(xs + (size_t)(c) * 512, (char*)&xa[buf][0] + 2 * w * 512)

// panel frags for chunk c (4 ksteps) for expert group w — plain loads (R17-style)
#define LOADP(buf, c) do { \
    _Pragma("unroll") \
    for (int ks_ = 0; ks_ < 4; ++ks_) \
        pan[buf][ks_] = *(const f16x8*)&pw[(((size_t)w * 64 + (c) * 4 + ks_) * 64 + lane) * 8]; \
} while (0)

// compute chunk from xa[buf]: 4 ksteps x 1 MFMA; B row = lane&7 (tokens duplicated)
#define COMPUTE(buf) do { \
    _Pragma("unroll") \
    for (int ks_ = 0; ks_ < 4; ++ks_) { \
        const int col_ = ks_ * 128 + ((lane >> 4) << 5); \
        const f32x4 v0_ = *(const f32x4*)((const char*)&xa[buf][0] + rbase + ((col_)      ^ rswz)); \
        const f32x4 v1_ = *(const f32x4*)((const char*)&xa[buf][0] + rbase + ((col_ + 16) ^ rswz)); \
        f16x8 af_; \
        af_[0] = (_Float16)v0_[0]; af_[1] = (_Float16)v0_[1]; \
        af_[2] = (_Float16)v0_[2]; af_[3] = (_Float16)v0_[3]; \
        af_[4] = (_Float16)v1_[0]; af_[5] = (_Float16)v1_[1]; \
        af_[6] = (_Float16)v1_[2]; af_[7] = (_Float16)v1_[3]; \
        acc = __builtin_amdgcn_mfma_f32_16x16x32_f16(pan[buf][ks_], af_, acc, 0, 0, 0); \
    } \
} while (0)

__global__ __launch_bounds__(256)
void gate_fused(const float* __restrict__ x,
                const _Float16* __restrict__ pw,
                const float* __restrict__ W,
                float* __restrict__ out) {
    __shared__ float xa[2][1024];     // 2 x 4 KB: 8 rows x 512B, swizzled content
    __shared__ float lg[BLK_TOK][68]; // logits [token][expert], padded

    const int tid  = threadIdx.x;
    const int lane = tid & 63;
    const int w    = tid >> 6;        // expert group 0..3
    const int tokb = blockIdx.x * BLK_TOK;

    // ---- staging source (per-lane, pre-swizzled column; R17-verified involution) ----
    // wave w stages rows 2w (lanes 0-31) and 2w+1 (lanes 32-63)
    const int r  = 2 * w + (lane >> 5);               // 0..7
    const int sl = (lane & 31) * 16;                  // 16B slot within 512B row chunk
    const char* xs = (const char*)x + (size_t)(tokb + r) * (DDIM * 4) + (sl ^ (r << 4));

    // ---- frag-read geometry: row = lane&7 (8 tokens, duplicated for lanes 8-15) ----
    const int rbase = (lane & 7) * 512;
    const int rswz  = (lane & 7) << 4;

    f16x8 pan[2][4];
    f32x4 acc = { 0.f, 0.f, 0.f, 0.f };

    STAGE(0, 0);
    LOADP(0, 0);
    __syncthreads();                       // chunk 0 landed

#pragma unroll
    for (int c = 0; c < NCHK; ++c) {
        if (c + 1 < NCHK) {
            STAGE((c + 1) & 1, c + 1);     // direct-to-LDS, zero VGPR involvement
            LOADP((c + 1) & 1, c + 1);     // L2 panel frags for next chunk
        }
        COMPUTE(c & 1);
        __syncthreads();
    }

    // ---- logits -> LDS (C layout verified: token=lane&15, expert=(lane>>4)*4+j + w*16) ----
    if ((lane & 15) < BLK_TOK)
        *(f32x4*)&lg[lane & 15][w * 16 + ((lane >> 4) << 2)] = acc;
    __syncthreads();

    // ---- fused epilogue: wave w owns 2 tokens (verified structure + fast refine) ----
    float* __restrict__ outw = out;
    float* __restrict__ outi = out + (size_t)T_TOKENS * 2;

#pragma unroll 1
    for (int t = 0; t < 2; ++t) {
        const int lt  = w * 2 + t;
        const int tok = tokb + lt;
        const float l = lg[lt][lane];

        float v1v = l; int i1 = lane;
#pragma unroll
        for (int off = 32; off >= 1; off >>= 1) {
            const float ov = __shfl_xor(v1v, off);
            const int   oi = __shfl_xor(i1, off);
            if (ov > v1v || (ov == v1v && oi < i1)) { v1v = ov; i1 = oi; }
        }
        float v2v = (lane == i1) ? -INFINITY : l; int i2 = lane;
#pragma unroll
        for (int off = 32; off >= 1; off >>= 1) {
            const float ov = __shfl_xor(v2v, off);
            const int   oi = __shfl_xor(i2, off);
            if (ov > v2v || (ov == v2v && oi < i2)) { v2v = ov; i2 = oi; }
        }
        float v3v = (lane == i1 || lane == i2) ? -INFINITY : l; int i3 = lane;
#pragma unroll
        for (int off = 32; off >= 1; off >>= 1) {
            const float ov = __shfl_xor(v3v, off);
            const int   oi = __shfl_xor(i3, off);
            if (ov > v3v || (ov == v3v && oi < i3)) { v3v = ov; i3 = oi; }
        }

        const float p = expf(l - v1v);
        float s = p;
#pragma unroll
        for (int off = 32; off >= 1; off >>= 1) s += __shfl_xor(s, off);

        int iA = i1, iB = i2;
        if ((v1v - v2v) < REFINE_TAU || (v2v - v3v) < REFINE_TAU) {
            const float* __restrict__ xrow = x + (size_t)tok * DDIM;
            double La = dot_f64_fast(xrow, W + (size_t)i1 * DDIM, lane);
            double Lb = dot_f64_fast(xrow, W + (size_t)i2 * DDIM, lane);
            double Lc = dot_f64_fast(xrow, W + (size_t)i3 * DDIM, lane);
            int ia = i1, ib = i2, ic = i3;
            if (!better(La, ia, Lb, ib)) { double tv = La; La = Lb; Lb = tv; int ti = ia; ia = ib; ib = ti; }
            if (!better(Lb, ib, Lc, ic)) { double tv = Lb; Lb = Lc; Lc = tv; int ti = ib; ib = ic; ic = ti; }
            if (!better(La, ia, Lb, ib)) { double tv = La; La = Lb; Lb = tv; int ti = ia; ia = ib; ib = ti; }
            iA = ia; iB = ib;
        }

        const float pA = __shfl(p, iA);
        const float pB = __shfl(p, iB);
        const float pa_ = pA / s;
        const float pb_ = pB / s;
        const float inv = 1.0f / (pa_ + pb_ + 1e-9f);

        if (lane == 0) {
            const size_t tg2 = (size_t)tok;
            outw[tg2 * 2]     = pa_ * inv;
            outw[tg2 * 2 + 1] = pb_ * inv;
            outi[tg2 * 2]     = (float)iA;
            outi[tg2 * 2 + 1] = (float)iB;
        }
    }
}

extern "C" void kernel_launch(void* const* d_in, const int* in_sizes, int n_in,
                              void* d_out, int out_size, void* d_ws, size_t ws_size,
                              hipStream_t stream) {
    const float* x = (const float*)d_in[0];
    const float* W = (const float*)d_in[1];
    float* out = (float*)d_out;
    _Float16* pw = (_Float16*)d_ws;                 // 256 KB fp16 frag panel

    prep_w<<<NEXP * DDIM / 8 / 256, 256, 0, stream>>>(W, pw);
    gate_fused<<<NBLK, 256, 0, stream>>>(x, pw, W, out);
}

// Round 24
// 52.237 us; speedup vs baseline: 1.0917x; 1.0917x over previous
//
#include <hip/hip_runtime.h>
#include <hip/hip_bf16.h>
#include <hip/hip_fp16.h>
#include <math.h>

#define T_TOKENS 16384
#define DDIM 2048
#define NEXP 64
#define REFINE_TAU 4e-3f
#define NCHK 8                     // 8 chunks of 256 k (halved barrier count vs R17)
#define NBLK (T_TOKENS / 16)       // 1024 blocks, 16 tokens each

typedef _Float16 f16x8 __attribute__((ext_vector_type(8)));
typedef float f32x4 __attribute__((ext_vector_type(4)));

__device__ __forceinline__ void gload_lds16(const void* g, void* l) {
    __builtin_amdgcn_global_load_lds(
        (const __attribute__((address_space(1))) void*)g,
        (__attribute__((address_space(3))) void*)l, 16, 0, 0);
}

// ---------------- Kernel 0: W fp32 -> fp16 fragment-ordered panel ----------------
// (r,k) -> pw[((g*64 + ks)*64 + lane)*8 + j], g=r>>4, ks=k>>5,
// lane=((k>>3)&3)*16 + (r&15), j=k&7.  (A-frag mapping, verified R4-R23.)
__global__ __launch_bounds__(256)
void prep_w(const float* __restrict__ W, _Float16* __restrict__ pw) {
    const int t  = blockIdx.x * 256 + threadIdx.x;   // 0..16383
    const int r  = t >> 8;
    const int kc = (t & 255) * 8;
    const float* wp = &W[(size_t)r * DDIM + kc];
    const float4 a = *(const float4*)wp;
    const float4 b = *(const float4*)(wp + 4);
    const float f[8] = { a.x, a.y, a.z, a.w, b.x, b.y, b.z, b.w };
    f16x8 h;
#pragma unroll
    for (int j = 0; j < 8; ++j) h[j] = (_Float16)f[j];
    const int g = r >> 4, ks = kc >> 5;
    const int lane = (((kc >> 3) & 3) << 4) + (r & 15);
    *(f16x8*)&pw[(((size_t)g * 64 + ks) * 64 + lane) * 8] = h;
}

// ---------------- Kernel 1: 256k-chunk LDS-staged gate + fused top-2 ----------------
__device__ __forceinline__ bool better(double va, int ia, double vb, int ib) {
    return (va > vb) || (va == vb && ia < ib);
}

// fast wave-cooperative f64 dot (R16-verified)
__device__ __forceinline__ double dot_f64_fast(const float* __restrict__ xrow,
                                               const float* __restrict__ wr, int lane) {
    float4 xa[8], wa[8];
#pragma unroll
    for (int q = 0; q < 8; ++q) {
        xa[q] = *(const float4*)&xrow[q * 256 + lane * 4];
        wa[q] = *(const float4*)&wr[q * 256 + lane * 4];
    }
    double s0 = 0.0, s1 = 0.0, s2 = 0.0, s3 = 0.0;
#pragma unroll
    for (int q = 0; q < 8; ++q) {
        s0 = fma((double)xa[q].x, (double)wa[q].x, s0);
        s1 = fma((double)xa[q].y, (double)wa[q].y, s1);
        s2 = fma((double)xa[q].z, (double)wa[q].z, s2);
        s3 = fma((double)xa[q].w, (double)wa[q].w, s3);
    }
    double sd = (s0 + s1) + (s2 + s3);
#pragma unroll
    for (int off = 32; off >= 1; off >>= 1) sd += __shfl_xor(sd, off);
    return sd;
}

// stage chunk c (16 rows x 1024B) into xa[buf]: wave w stages rows 4w..4w+3,
// each gload_lds issue = exactly one 1024B row. Source pre-swizzled (R17 involution).
#define STAGE(buf, c) do { \
    gload_lds16(xsrc0 + (size_t)(c) * 1024, (char*)&xa[buf][0] + (4 * w + 0) * 1024); \
    gload_lds16(xsrc1 + (size_t)(c) * 1024, (char*)&xa[buf][0] + (4 * w + 1) * 1024); \
    gload_lds16(xsrc2 + (size_t)(c) * 1024, (char*)&xa[buf][0] + (4 * w + 2) * 1024); \
    gload_lds16(xsrc3 + (size_t)(c) * 1024, (char*)&xa[buf][0] + (4 * w + 3) * 1024); \
} while (0)

// panel frags for chunk c (8 ksteps) for expert group w, contiguous 1KB wave-loads
#define LOADP(buf, c) do { \
    _Pragma("unroll") \
    for (int ks_ = 0; ks_ < 8; ++ks_) \
        pan[buf][ks_] = *(const f16x8*)&pw[(((size_t)w * 64 + (c) * 8 + ks_) * 64 + lane) * 8]; \
} while (0)

// compute chunk from xa[buf]: 8 ksteps x 1 MFMA
#define COMPUTE(buf) do { \
    _Pragma("unroll") \
    for (int ks_ = 0; ks_ < 8; ++ks_) { \
        const int col_ = ks_ * 128 + ((lane >> 4) << 5); \
        const f32x4 v0_ = *(const f32x4*)((const char*)&xa[buf][0] + rbase + ((col_)      ^ rswz)); \
        const f32x4 v1_ = *(const f32x4*)((const char*)&xa[buf][0] + rbase + ((col_ + 16) ^ rswz)); \
        f16x8 af_; \
        af_[0] = (_Float16)v0_[0]; af_[1] = (_Float16)v0_[1]; \
        af_[2] = (_Float16)v0_[2]; af_[3] = (_Float16)v0_[3]; \
        af_[4] = (_Float16)v1_[0]; af_[5] = (_Float16)v1_[1]; \
        af_[6] = (_Float16)v1_[2]; af_[7] = (_Float16)v1_[3]; \
        acc = __builtin_amdgcn_mfma_f32_16x16x32_f16(pan[buf][ks_], af_, acc, 0, 0, 0); \
    } \
} while (0)

__global__ __launch_bounds__(256)
void gate_fused(const float* __restrict__ x,
                const _Float16* __restrict__ pw,
                const float* __restrict__ W,
                float* __restrict__ out) {
    __shared__ float xa[2][4096];     // 2 x 16 KB: 16 rows x 1024B, swizzled content
    __shared__ float lg[16][68];      // logits [token][expert], padded

    const int tid  = threadIdx.x;
    const int lane = tid & 63;
    const int w    = tid >> 6;        // expert group 0..3
    const int tokb = blockIdx.x * 16;

    // ---- staging sources: row rj = 4w+j; lane byte (lane*16) ^ ((rj&7)<<4) ----
    const int rr0 = 4 * w, rr1 = 4 * w + 1, rr2 = 4 * w + 2, rr3 = 4 * w + 3;
    const char* xsrc0 = (const char*)x + (size_t)(tokb + rr0) * (DDIM * 4) + ((lane * 16) ^ ((rr0 & 7) << 4));
    const char* xsrc1 = (const char*)x + (size_t)(tokb + rr1) * (DDIM * 4) + ((lane * 16) ^ ((rr1 & 7) << 4));
    const char* xsrc2 = (const char*)x + (size_t)(tokb + rr2) * (DDIM * 4) + ((lane * 16) ^ ((rr2 & 7) << 4));
    const char* xsrc3 = (const char*)x + (size_t)(tokb + rr3) * (DDIM * 4) + ((lane * 16) ^ ((rr3 & 7) << 4));

    // ---- frag-read geometry: row = lane&15 (1024B rows); (row&7) == (lane&7) ----
    const int rbase = (lane & 15) * 1024;
    const int rswz  = (lane & 7) << 4;

    f16x8 pan[2][8];
    f32x4 acc = { 0.f, 0.f, 0.f, 0.f };

    STAGE(0, 0);
    LOADP(0, 0);
    __syncthreads();                       // chunk 0 landed

#pragma unroll
    for (int c = 0; c < NCHK; ++c) {
        if (c + 1 < NCHK) {
            STAGE((c + 1) & 1, c + 1);     // direct-to-LDS, zero VGPR involvement
            LOADP((c + 1) & 1, c + 1);     // L2 panel frags for next chunk
        }
        COMPUTE(c & 1);
        __syncthreads();
    }

    // ---- logits -> LDS (C layout verified: token=lane&15, expert=(lane>>4)*4+j + w*16) ----
    *(f32x4*)&lg[lane & 15][w * 16 + ((lane >> 4) << 2)] = acc;
    __syncthreads();

    // ---- fused epilogue: wave w owns 4 tokens (verified structure + fast refine) ----
    float* __restrict__ outw = out;
    float* __restrict__ outi = out + (size_t)T_TOKENS * 2;

#pragma unroll 1
    for (int t = 0; t < 4; ++t) {
        const int lt  = w * 4 + t;
        const int tok = tokb + lt;
        const float l = lg[lt][lane];

        float v1v = l; int i1 = lane;
#pragma unroll
        for (int off = 32; off >= 1; off >>= 1) {
            const float ov = __shfl_xor(v1v, off);
            const int   oi = __shfl_xor(i1, off);
            if (ov > v1v || (ov == v1v && oi < i1)) { v1v = ov; i1 = oi; }
        }
        float v2v = (lane == i1) ? -INFINITY : l; int i2 = lane;
#pragma unroll
        for (int off = 32; off >= 1; off >>= 1) {
            const float ov = __shfl_xor(v2v, off);
            const int   oi = __shfl_xor(i2, off);
            if (ov > v2v || (ov == v2v && oi < i2)) { v2v = ov; i2 = oi; }
        }
        float v3v = (lane == i1 || lane == i2) ? -INFINITY : l; int i3 = lane;
#pragma unroll
        for (int off = 32; off >= 1; off >>= 1) {
            const float ov = __shfl_xor(v3v, off);
            const int   oi = __shfl_xor(i3, off);
            if (ov > v3v || (ov == v3v && oi < i3)) { v3v = ov; i3 = oi; }
        }

        const float p = expf(l - v1v);
        float s = p;
#pragma unroll
        for (int off = 32; off >= 1; off >>= 1) s += __shfl_xor(s, off);

        int iA = i1, iB = i2;
        if ((v1v - v2v) < REFINE_TAU || (v2v - v3v) < REFINE_TAU) {
            const float* __restrict__ xrow = x + (size_t)tok * DDIM;
            double La = dot_f64_fast(xrow, W + (size_t)i1 * DDIM, lane);
            double Lb = dot_f64_fast(xrow, W + (size_t)i2 * DDIM, lane);
            double Lc = dot_f64_fast(xrow, W + (size_t)i3 * DDIM, lane);
            int ia = i1, ib = i2, ic = i3;
            if (!better(La, ia, Lb, ib)) { double tv = La; La = Lb; Lb = tv; int ti = ia; ia = ib; ib = ti; }
            if (!better(Lb, ib, Lc, ic)) { double tv = Lb; Lb = Lc; Lc = tv; int ti = ib; ib = ic; ic = ti; }
            if (!better(La, ia, Lb, ib)) { double tv = La; La = Lb; Lb = tv; int ti = ia; ia = ib; ib = ti; }
            iA = ia; iB = ib;
        }

        const float pA = __shfl(p, iA);
        const float pB = __shfl(p, iB);
        const float pa_ = pA / s;
        const float pb_ = pB / s;
        const float inv = 1.0f / (pa_ + pb_ + 1e-9f);

        if (lane == 0) {
            const size_t tg2 = (size_t)tok;
            outw[tg2 * 2]     = pa_ * inv;
            outw[tg2 * 2 + 1] = pb_ * inv;
            outi[tg2 * 2]     = (float)iA;
            outi[tg2 * 2 + 1] = (float)iB;
        }
    }
}

extern "C" void kernel_launch(void* const* d_in, const int* in_sizes, int n_in,
                              void* d_out, int out_size, void* d_ws, size_t ws_size,
                              hipStream_t stream) {
    const float* x = (const float*)d_in[0];
    const float* W = (const float*)d_in[1];
    float* out = (float*)d_out;
    _Float16* pw = (_Float16*)d_ws;                 // 256 KB fp16 frag panel

    prep_w<<<NEXP * DDIM / 8 / 256, 256, 0, stream>>>(W, pw);
    gate_fused<<<NBLK, 256, 0, stream>>>(x, pw, W, out);
}

// Round 25
// 45.286 us; speedup vs baseline: 1.2592x; 1.1535x over previous
//
#include <hip/hip_runtime.h>
#include <hip/hip_bf16.h>
#include <hip/hip_fp16.h>
#include <math.h>

#define T_TOKENS 16384
#define DDIM 2048
#define NEXP 64
#define REFINE_TAU 4e-3f
#define NCHK 16                    // 16 chunks of 128 k
#define NBLK (T_TOKENS / 16)       // 1024 blocks, 16 tokens each

typedef _Float16 f16x8 __attribute__((ext_vector_type(8)));
typedef float f32x4 __attribute__((ext_vector_type(4)));

__device__ __forceinline__ void gload_lds16(const void* g, void* l) {
    __builtin_amdgcn_global_load_lds(
        (const __attribute__((address_space(1))) void*)g,
        (__attribute__((address_space(3))) void*)l, 16, 0, 0);
}

// ---------------- Kernel 0: W fp32 -> fp16 fragment-ordered panel ----------------
// (r,k) -> pw[((g*64 + ks)*64 + lane)*8 + j], g=r>>4, ks=k>>5,
// lane=((k>>3)&3)*16 + (r&15), j=k&7.  (A-frag mapping, verified R4-R24.)
__global__ __launch_bounds__(256)
void prep_w(const float* __restrict__ W, _Float16* __restrict__ pw) {
    const int t  = blockIdx.x * 256 + threadIdx.x;   // 0..16383
    const int r  = t >> 8;
    const int kc = (t & 255) * 8;
    const float* wp = &W[(size_t)r * DDIM + kc];
    const float4 a = *(const float4*)wp;
    const float4 b = *(const float4*)(wp + 4);
    const float f[8] = { a.x, a.y, a.z, a.w, b.x, b.y, b.z, b.w };
    f16x8 h;
#pragma unroll
    for (int j = 0; j < 8; ++j) h[j] = (_Float16)f[j];
    const int g = r >> 4, ks = kc >> 5;
    const int lane = (((kc >> 3) & 3) << 4) + (r & 15);
    *(f16x8*)&pw[(((size_t)g * 64 + ks) * 64 + lane) * 8] = h;
}

// ---------------- Kernel 1: row-contiguous LDS-staged gate + fused top-2 ----------------
__device__ __forceinline__ bool better(double va, int ia, double vb, int ib) {
    return (va > vb) || (va == vb && ia < ib);
}

// fast wave-cooperative f64 dot (R16-verified): 16 coalesced loads up-front,
// 4 independent FMA chains, then 6-level butterfly.
__device__ __forceinline__ double dot_f64_fast(const float* __restrict__ xrow,
                                               const float* __restrict__ wr, int lane) {
    float4 xa[8], wa[8];
#pragma unroll
    for (int q = 0; q < 8; ++q) {
        xa[q] = *(const float4*)&xrow[q * 256 + lane * 4];
        wa[q] = *(const float4*)&wr[q * 256 + lane * 4];
    }
    double s0 = 0.0, s1 = 0.0, s2 = 0.0, s3 = 0.0;
#pragma unroll
    for (int q = 0; q < 8; ++q) {
        s0 = fma((double)xa[q].x, (double)wa[q].x, s0);
        s1 = fma((double)xa[q].y, (double)wa[q].y, s1);
        s2 = fma((double)xa[q].z, (double)wa[q].z, s2);
        s3 = fma((double)xa[q].w, (double)wa[q].w, s3);
    }
    double sd = (s0 + s1) + (s2 + s3);
#pragma unroll
    for (int off = 32; off >= 1; off >>= 1) sd += __shfl_xor(sd, off);
    return sd;
}

// stage chunk c into xa[buf]: wave w covers rows 4w..4w+3, two 1KB issues.
// Source col pre-swizzled (m173): LDS stays linear, read side applies the XOR.
#define STAGE(buf, c) do { \
    gload_lds16(xs0 + (size_t)(c) * 512, (char*)&xa[buf][0] + (4 * w)     * 512); \
    gload_lds16(xs1 + (size_t)(c) * 512, (char*)&xa[buf][0] + (4 * w + 2) * 512); \
} while (0)

// panel frags for chunk c (4 ksteps), contiguous 1KB wave-loads from L2
#define LOADP(buf, c) do { \
    _Pragma("unroll") \
    for (int ks_ = 0; ks_ < 4; ++ks_) \
        pan[buf][ks_] = *(const f16x8*)&pw[(((size_t)w * 64 + (c) * 4 + ks_) * 64 + lane) * 8]; \
} while (0)

// compute chunk c from xa[buf]: 4 ksteps x 1 MFMA
#define COMPUTE(buf) do { \
    _Pragma("unroll") \
    for (int ks_ = 0; ks_ < 4; ++ks_) { \
        const int col_ = ks_ * 128 + ((lane >> 4) << 5); \
        const f32x4 v0_ = *(const f32x4*)((const char*)&xa[buf][0] + rbase + ((col_)      ^ rswz)); \
        const f32x4 v1_ = *(const f32x4*)((const char*)&xa[buf][0] + rbase + ((col_ + 16) ^ rswz)); \
        f16x8 af_; \
        af_[0] = (_Float16)v0_[0]; af_[1] = (_Float16)v0_[1]; \
        af_[2] = (_Float16)v0_[2]; af_[3] = (_Float16)v0_[3]; \
        af_[4] = (_Float16)v1_[0]; af_[5] = (_Float16)v1_[1]; \
        af_[6] = (_Float16)v1_[2]; af_[7] = (_Float16)v1_[3]; \
        acc = __builtin_amdgcn_mfma_f32_16x16x32_f16(pan[buf][ks_], af_, acc, 0, 0, 0); \
    } \
} while (0)

__global__ __launch_bounds__(256)
void gate_fused(const float* __restrict__ x,
                const _Float16* __restrict__ pw,
                const float* __restrict__ W,
                float* __restrict__ out) {
    __shared__ float xa[2][2048];     // 2 x 8 KB: 16 rows x 512B, XOR-swizzled content
    __shared__ float lg[16][68];      // logits [token][expert], padded

    const int tid  = threadIdx.x;
    const int lane = tid & 63;
    const int w    = tid >> 6;        // expert group 0..3
    const int tokb = blockIdx.x * 16;

    // ---- staging source (per-lane, pre-swizzled column) ----
    const int r0 = 4 * w + (lane >> 5);
    const int r1 = 4 * w + 2 + (lane >> 5);
    const int v0 = ((lane & 31) * 16) ^ ((r0 & 7) << 4);
    const int v1 = ((lane & 31) * 16) ^ ((r1 & 7) << 4);
    const char* xs0 = (const char*)x + (size_t)(tokb + r0) * (DDIM * 4) + v0;
    const char* xs1 = (const char*)x + (size_t)(tokb + r1) * (DDIM * 4) + v1;

    // ---- frag-read geometry: row = lane&15, swizzle on the column part ----
    const int rbase = (lane & 15) * 512;
    const int rswz  = (lane & 7) << 4;

    f16x8 pan[2][4];
    f32x4 acc = { 0.f, 0.f, 0.f, 0.f };

    STAGE(0, 0);
    LOADP(0, 0);
    __syncthreads();                       // chunk 0 landed

#pragma unroll
    for (int c = 0; c < NCHK; ++c) {
        if (c + 1 < NCHK) {
            STAGE((c + 1) & 1, c + 1);     // direct-to-LDS, zero VGPR involvement
            LOADP((c + 1) & 1, c + 1);     // L2 panel frags for next chunk
        }
        COMPUTE(c & 1);
        __syncthreads();
    }

    // ---- logits -> LDS (C layout verified: token=lane&15, expert=(lane>>4)*4+j + w*16) ----
    *(f32x4*)&lg[lane & 15][w * 16 + ((lane >> 4) << 2)] = acc;
    __syncthreads();

    // ---- fused epilogue: wave w owns 4 tokens (verified structure + fast refine) ----
    float* __restrict__ outw = out;
    float* __restrict__ outi = out + (size_t)T_TOKENS * 2;

#pragma unroll 1
    for (int t = 0; t < 4; ++t) {
        const int lt  = w * 4 + t;
        const int tok = tokb + lt;
        const float l = lg[lt][lane];

        float v1v = l; int i1 = lane;
#pragma unroll
        for (int off = 32; off >= 1; off >>= 1) {
            const float ov = __shfl_xor(v1v, off);
            const int   oi = __shfl_xor(i1, off);
            if (ov > v1v || (ov == v1v && oi < i1)) { v1v = ov; i1 = oi; }
        }
        float v2v = (lane == i1) ? -INFINITY : l; int i2 = lane;
#pragma unroll
        for (int off = 32; off >= 1; off >>= 1) {
            const float ov = __shfl_xor(v2v, off);
            const int   oi = __shfl_xor(i2, off);
            if (ov > v2v || (ov == v2v && oi < i2)) { v2v = ov; i2 = oi; }
        }
        float v3v = (lane == i1 || lane == i2) ? -INFINITY : l; int i3 = lane;
#pragma unroll
        for (int off = 32; off >= 1; off >>= 1) {
            const float ov = __shfl_xor(v3v, off);
            const int   oi = __shfl_xor(i3, off);
            if (ov > v3v || (ov == v3v && oi < i3)) { v3v = ov; i3 = oi; }
        }

        const float p = expf(l - v1v);
        float s = p;
#pragma unroll
        for (int off = 32; off >= 1; off >>= 1) s += __shfl_xor(s, off);

        int iA = i1, iB = i2;
        if ((v1v - v2v) < REFINE_TAU || (v2v - v3v) < REFINE_TAU) {
            const float* __restrict__ xrow = x + (size_t)tok * DDIM;
            double La = dot_f64_fast(xrow, W + (size_t)i1 * DDIM, lane);
            double Lb = dot_f64_fast(xrow, W + (size_t)i2 * DDIM, lane);
            double Lc = dot_f64_fast(xrow, W + (size_t)i3 * DDIM, lane);
            int ia = i1, ib = i2, ic = i3;
            if (!better(La, ia, Lb, ib)) { double tv = La; La = Lb; Lb = tv; int ti = ia; ia = ib; ib = ti; }
            if (!better(Lb, ib, Lc, ic)) { double tv = Lb; Lb = Lc; Lc = tv; int ti = ib; ib = ic; ic = ti; }
            if (!better(La, ia, Lb, ib)) { double tv = La; La = Lb; Lb = tv; int ti = ia; ia = ib; ib = ti; }
            iA = ia; iB = ib;
        }

        const float pA = __shfl(p, iA);
        const float pB = __shfl(p, iB);
        const float pa_ = pA / s;
        const float pb_ = pB / s;
        const float inv = 1.0f / (pa_ + pb_ + 1e-9f);

        if (lane == 0) {
            const size_t tg2 = (size_t)tok;
            outw[tg2 * 2]     = pa_ * inv;
            outw[tg2 * 2 + 1] = pb_ * inv;
            outi[tg2 * 2]     = (float)iA;
            outi[tg2 * 2 + 1] = (float)iB;
        }
    }
}

extern "C" void kernel_launch(void* const* d_in, const int* in_sizes, int n_in,
                              void* d_out, int out_size, void* d_ws, size_t ws_size,
                              hipStream_t stream) {
    const float* x = (const float*)d_in[0];
    const float* W = (const float*)d_in[1];
    float* out = (float*)d_out;
    _Float16* pw = (_Float16*)d_ws;                 // 256 KB fp16 frag panel

    prep_w<<<NEXP * DDIM / 8 / 256, 256, 0, stream>>>(W, pw);
    gate_fused<<<NBLK, 256, 0, stream>>>(x, pw, W, out);
}